// Round 12
// baseline (345.057 us; speedup 1.0000x reference)
//
#include <hip/hip_runtime.h>
#include <stdint.h>
#include <stddef.h>

// Mamba block, B=4 L=2048 D=DI=1024 N=8 K=4 R=64. I/O fp32; GEMMs fp16 MFMA.
// Round 12: second fix of gemm128 bank conflicts. R10+R11 both measured
// EXACTLY 4 extra cyc/ds_read_b128 -> refined HW model: b128 reads service
// 8 CONSECUTIVE LANES per phase; conflicts = same 16B quad within those 8.
// gemm1b's q^(cl&7) is an 8-lane bijection (0 conflicts); R11's
// (2q+(cl&1))^((cl>>1)&7) pairs up (2-way). New mapping is an 8-lane
// bijection: granule (row,kc) in super-row sr at quad (kc+4*(row&1))^(sr&7);
// read quad = (q+4*(cl&1))^((cl>>1)&7): even lanes cover [0,3], odd [4,7],
// all distinct within any 8 consecutive lanes. Staging inversion: granule i
// -> t=(i&7)^((i>>3)&7), row=(i>>3)*2+(t>>2), kc=t&3. MFMA operands per lane
// unchanged -> numerics identical. Single change vs round 11.
// Dispatches: prep -> in_proj(gemm128) -> conv -> x_proj -> dtproj -> scan1
//   -> combine -> scan2 -> out_proj(gemm1b<128,1>). ws unchanged (115 MiB).

typedef unsigned short u16;
typedef unsigned int u32;
typedef _Float16 f16;
typedef __attribute__((ext_vector_type(8))) _Float16 half8;
typedef __attribute__((ext_vector_type(4))) _Float16 half4;
typedef __attribute__((ext_vector_type(4))) float f32x4;

#define LSEQ 2048
#define DMODEL 1024
#define NSTATE 8
#define NCHUNK 64
#define CHUNKL 32
#define NROWS 8192
#define WS_NEED (115ull << 20)

__device__ __forceinline__ void gload_lds16(const void* g, void* l) {
    __builtin_amdgcn_global_load_lds((__attribute__((address_space(1))) void*)g,
                                     (__attribute__((address_space(3))) void*)l,
                                     16, 0, 0);
}

__global__ __launch_bounds__(256) void sentinel_kernel(float* __restrict__ out, int n) {
    int i = blockIdx.x * 256 + threadIdx.x;
    if (i < n) out[i] = 999.0f;
}

// ---- prep: weight fp32->fp16 (4 tensors) + zero dbl_f + rmsnorm ----
#define T0 524288   // in_proj_w /4
#define T1 20480    // x_proj_w /4
#define T2 16384    // dt_proj_w /4
#define T3 262144   // out_proj_w /4
#define WCVT_BLK 3216          // (T0+T1+T2+T3)/256
#define ZERO_BLK 640           // 8192*80*4B / 16B / 256
__global__ __launch_bounds__(256) void prep_kernel(const float* __restrict__ s0,
                                                   const float* __restrict__ s1,
                                                   const float* __restrict__ s2,
                                                   const float* __restrict__ s3,
                                                   f16* __restrict__ d0, f16* __restrict__ d1,
                                                   f16* __restrict__ d2, f16* __restrict__ d3,
                                                   float* __restrict__ dblz,
                                                   const float* __restrict__ X,
                                                   const float* __restrict__ W,
                                                   f16* __restrict__ O) {
    const int bx = blockIdx.x;
    const int tid = threadIdx.x;
    if (bx < WCVT_BLK) {
        int idx = bx * 256 + tid;
        const float* s; f16* d; int i;
        if (idx < T0) { s = s0; d = d0; i = idx; }
        else if (idx < T0 + T1) { s = s1; d = d1; i = idx - T0; }
        else if (idx < T0 + T1 + T2) { s = s2; d = d2; i = idx - T0 - T1; }
        else { s = s3; d = d3; i = idx - T0 - T1 - T2; }
        f32x4 v = *(const f32x4*)(s + (size_t)i * 4);
        half4 o; o[0] = (f16)v[0]; o[1] = (f16)v[1]; o[2] = (f16)v[2]; o[3] = (f16)v[3];
        *(half4*)(d + (size_t)i * 4) = o;
    } else if (bx < WCVT_BLK + ZERO_BLK) {
        int i = (bx - WCVT_BLK) * 256 + tid;
        const f32x4 z4 = {0.f, 0.f, 0.f, 0.f};
        ((f32x4*)dblz)[i] = z4;
    } else {
        const int row = bx - (WCVT_BLK + ZERO_BLK);
        f32x4 u = *(const f32x4*)(X + (size_t)row * DMODEL + tid * 4);
        float ss = u[0]*u[0] + u[1]*u[1] + u[2]*u[2] + u[3]*u[3];
        for (int off = 32; off; off >>= 1) ss += __shfl_down(ss, off, 64);
        __shared__ float red[4];
        if ((tid & 63) == 0) red[tid >> 6] = ss;
        __syncthreads();
        float tot = red[0] + red[1] + red[2] + red[3];
        float scale = rsqrtf(tot * (1.0f / DMODEL) + 1e-5f);
        f32x4 w = *(const f32x4*)(W + tid * 4);
        half4 o;
        o[0] = (f16)(u[0] * scale * w[0]); o[1] = (f16)(u[1] * scale * w[1]);
        o[2] = (f16)(u[2] * scale * w[2]); o[3] = (f16)(u[3] * scale * w[3]);
        *(half4*)(O + (size_t)row * DMODEL + tid * 4) = o;
    }
}

// ====== high-occupancy 128x256 BK=32 GEMM (in_proj), super-row LDS v2 =======
// C[m,n] = sum_k A[m,k]*Bm[n,k]. 512 thr (8 waves 2Mx4N, wave = 64x64 out).
// LDS dbuf: sA 2x[64 super-rows][128B], sB 2x[128 super-rows][128B].
// Granule (row,kc) -> super-row row>>1, quad (kc+4*(row&1))^((row>>1)&7):
// quad is a BIJECTION over any 8 consecutive lanes (even lanes [0,3], odd
// [4,7]) -> conflict-free under the 8-lane-phase model. Pre-permuted global
// source (linear gload dest). Swapped-operand MFMA; half4 split stores.
__global__ __launch_bounds__(512, 4) void gemm128(const f16* __restrict__ Ap, int lda,
                                                  const f16* __restrict__ Bm, int ldb,
                                                  f16* __restrict__ C0, f16* __restrict__ C1,
                                                  int KT) {
    __shared__ alignas(16) f16 sA[2 * 128 * 32];   // 16 KiB
    __shared__ alignas(16) f16 sB[2 * 256 * 32];   // 32 KiB
    const int tid = threadIdx.x;
    const int wave = tid >> 6, lane = tid & 63;
    const int wm = wave >> 2, wn = wave & 3;       // 2M x 4N waves
    const int cl = lane & 15, q = lane >> 4;
    const int tm = blockIdx.x, tn = blockIdx.y;

    // staging: thread owns LDS granule i (A: i=tid; B: i=tid and 512+tid).
    // invert layout: t = (i&7)^((i>>3)&7) -> row=(i>>3)*2+(t>>2), kc=t&3.
    const int tA = (tid & 7) ^ ((tid >> 3) & 7);
    const f16* aG = Ap + (size_t)(tm * 128 + (tid >> 3) * 2 + (tA >> 2)) * lda + (tA & 3) * 8;
    const int iB1 = 512 + tid;
    const int tB0 = (tid & 7) ^ ((tid >> 3) & 7);
    const int tB1 = (iB1 & 7) ^ ((iB1 >> 3) & 7);
    const f16* bG0 = Bm + (size_t)(tn * 256 + (tid >> 3) * 2 + (tB0 >> 2)) * ldb + (tB0 & 3) * 8;
    const f16* bG1 = Bm + (size_t)(tn * 256 + (iB1 >> 3) * 2 + (tB1 >> 2)) * ldb + (tB1 & 3) * 8;

    // read: lane (cl,q) frag f -> super-row wm*32 + f*8 + (cl>>1),
    // quad = (q + 4*(cl&1)) ^ ((cl>>1)&7)  (bijective over 8 consecutive lanes).
    const int quad = (q + 4 * (cl & 1)) ^ ((cl >> 1) & 7);
    const int rdA = (wm * 32 + (cl >> 1)) * 64 + quad * 8;   // + f*512
    const int rdB = (wn * 32 + (cl >> 1)) * 64 + quad * 8;   // + g*512

    f32x4 acc[4][4];
    const f32x4 zero4 = {0.f, 0.f, 0.f, 0.f};
#pragma unroll
    for (int f = 0; f < 4; f++)
#pragma unroll
        for (int g = 0; g < 4; g++) acc[f][g] = zero4;

    auto STAGE = [&](int tt) {
        gload_lds16(aG + (size_t)tt * 32, sA + (tt & 1) * 4096 + tid * 8);
        gload_lds16(bG0 + (size_t)tt * 32, sB + (tt & 1) * 8192 + tid * 8);
        gload_lds16(bG1 + (size_t)tt * 32, sB + (tt & 1) * 8192 + 4096 + tid * 8);
    };

    // prologue: stage tile 0, drain, rendezvous.
    STAGE(0);
    asm volatile("s_waitcnt vmcnt(0)" ::: "memory");
    __builtin_amdgcn_s_barrier();
    __builtin_amdgcn_sched_barrier(0);

    for (int t = 0; t < KT; t++) {
        const f16* sAb = sA + (t & 1) * 4096;
        const f16* sBb = sB + (t & 1) * 8192;

        if (t + 1 < KT) STAGE(t + 1);
        __builtin_amdgcn_sched_barrier(0);

        half8 a[4], b[4];
#pragma unroll
        for (int f = 0; f < 4; f++) a[f] = *(const half8*)(sAb + rdA + f * 512);
#pragma unroll
        for (int g = 0; g < 4; g++) b[g] = *(const half8*)(sBb + rdB + g * 512);
        __builtin_amdgcn_s_setprio(1);
#pragma unroll
        for (int f = 0; f < 4; f++)
#pragma unroll
            for (int g = 0; g < 4; g++)
                acc[f][g] = __builtin_amdgcn_mfma_f32_16x16x32_f16(b[g], a[f], acc[f][g], 0, 0, 0);
        __builtin_amdgcn_s_setprio(0);

        if (t + 1 < KT) {
            asm volatile("s_waitcnt vmcnt(0)" ::: "memory");
            __builtin_amdgcn_s_barrier();
            __builtin_amdgcn_sched_barrier(0);
        }
    }

    // epilogue (swapped layout): lane holds m = cl (+f*16), n = q*4 (+g*16).
    const int rowb = tm * 128 + wm * 64 + cl;
    const int colb = tn * 256 + wn * 64 + q * 4;
#pragma unroll
    for (int f = 0; f < 4; f++) {
        size_t ro = (size_t)(rowb + f * 16) * 1024;
#pragma unroll
        for (int g = 0; g < 4; g++) {
            int nb = colb + g * 16;
            f32x4 v = acc[f][g];
            half4 hv;
            hv[0] = (f16)v[0]; hv[1] = (f16)v[1]; hv[2] = (f16)v[2]; hv[3] = (f16)v[3];
            if (nb < 1024) *(half4*)(C0 + ro + nb) = hv;
            else           *(half4*)(C1 + ro + nb - 1024) = hv;
        }
    }
}

// ====== one-barrier-per-K-tile free-form 256xBN GEMM (out_proj) =============
template <int BN, int EPI>
__global__ __launch_bounds__(512, 2) void gemm1b(const f16* __restrict__ Ap, int lda,
                                                 const f16* __restrict__ Bm, int ldb,
                                                 void* __restrict__ C0, void* __restrict__ C1,
                                                 int KT) {
    constexpr int Wn = BN / 4;                 // wave col width: 64 or 32
    constexpr int NF = Wn / 16;                // col frags per wave: 4 or 2
    __shared__ alignas(16) f16 sA[2 * 256 * 64];
    __shared__ alignas(16) f16 sB[2 * BN * 64];
    const int tid = threadIdx.x;
    const int wave = tid >> 6, lane = tid & 63;
    const int wm = wave >> 2, wn = wave & 3;   // 2M x 4N waves
    const int cl = lane & 15, q = lane >> 4;
    const int tm = blockIdx.x, tn = blockIdx.y;

    const int srow = tid >> 3;
    const int skc = (tid & 7) ^ (srow & 7);
    const f16* aG = Ap + (size_t)(tm * 256 + srow) * lda + skc * 8;
    const f16* bG = Bm + (size_t)(tn * BN + srow) * ldb + skc * 8;
    const int ldsW = wave * 512;

    const int swz0 = (q ^ (cl & 7)) << 3;
    const int swz1 = ((4 + q) ^ (cl & 7)) << 3;
    const int rdA0 = (wm * 128 + cl) * 64 + swz0;
    const int rdA1 = (wm * 128 + cl) * 64 + swz1;
    const int rdB0 = (wn * Wn + cl) * 64 + swz0;
    const int rdB1 = (wn * Wn + cl) * 64 + swz1;

    f32x4 acc[8][NF];
    const f32x4 zero4 = {0.f, 0.f, 0.f, 0.f};
#pragma unroll
    for (int f = 0; f < 8; f++)
#pragma unroll
        for (int g = 0; g < NF; g++) acc[f][g] = zero4;

    auto STAGE = [&](int tt) {
#pragma unroll
        for (int h = 0; h < 4; h++)
            gload_lds16(aG + (size_t)tt * 64 + (size_t)(h * 64) * lda,
                        sA + (tt & 1) * 16384 + h * 4096 + ldsW);
#pragma unroll
        for (int h = 0; h < BN / 64; h++)
            gload_lds16(bG + (size_t)tt * 64 + (size_t)(h * 64) * ldb,
                        sB + (tt & 1) * (BN * 64) + h * 4096 + ldsW);
    };

    STAGE(0);
    asm volatile("s_waitcnt vmcnt(0)" ::: "memory");
    __builtin_amdgcn_s_barrier();
    __builtin_amdgcn_sched_barrier(0);

    for (int t = 0; t < KT; t++) {
        const f16* sAb = sA + (t & 1) * 16384;
        const f16* sBb = sB + (t & 1) * (BN * 64);

        if (t + 1 < KT) STAGE(t + 1);
        __builtin_amdgcn_sched_barrier(0);

        if constexpr (BN == 256) {
            half8 a0[4][2], a1[4][2], b0[2][2], b1[2][2];
#pragma unroll
            for (int f = 0; f < 4; f++) {
                a0[f][0] = *(const half8*)(sAb + rdA0 + f * 1024);
                a0[f][1] = *(const half8*)(sAb + rdA1 + f * 1024);
            }
#pragma unroll
            for (int g = 0; g < 2; g++) {
                b0[g][0] = *(const half8*)(sBb + rdB0 + g * 1024);
                b0[g][1] = *(const half8*)(sBb + rdB1 + g * 1024);
            }
            __builtin_amdgcn_s_setprio(1);
#pragma unroll
            for (int f = 0; f < 4; f++)
#pragma unroll
                for (int g = 0; g < 2; g++) {
                    acc[f][g] = __builtin_amdgcn_mfma_f32_16x16x32_f16(b0[g][0], a0[f][0], acc[f][g], 0, 0, 0);
                    acc[f][g] = __builtin_amdgcn_mfma_f32_16x16x32_f16(b0[g][1], a0[f][1], acc[f][g], 0, 0, 0);
                }
#pragma unroll
            for (int g = 0; g < 2; g++) {
                b1[g][0] = *(const half8*)(sBb + rdB0 + (2 + g) * 1024);
                b1[g][1] = *(const half8*)(sBb + rdB1 + (2 + g) * 1024);
            }
#pragma unroll
            for (int f = 0; f < 4; f++)
#pragma unroll
                for (int g = 0; g < 2; g++) {
                    acc[f][2 + g] = __builtin_amdgcn_mfma_f32_16x16x32_f16(b1[g][0], a0[f][0], acc[f][2 + g], 0, 0, 0);
                    acc[f][2 + g] = __builtin_amdgcn_mfma_f32_16x16x32_f16(b1[g][1], a0[f][1], acc[f][2 + g], 0, 0, 0);
                }
#pragma unroll
            for (int f = 0; f < 4; f++) {
                a1[f][0] = *(const half8*)(sAb + rdA0 + (4 + f) * 1024);
                a1[f][1] = *(const half8*)(sAb + rdA1 + (4 + f) * 1024);
            }
#pragma unroll
            for (int f = 0; f < 4; f++)
#pragma unroll
                for (int g = 0; g < 2; g++) {
                    acc[4 + f][2 + g] = __builtin_amdgcn_mfma_f32_16x16x32_f16(b1[g][0], a1[f][0], acc[4 + f][2 + g], 0, 0, 0);
                    acc[4 + f][2 + g] = __builtin_amdgcn_mfma_f32_16x16x32_f16(b1[g][1], a1[f][1], acc[4 + f][2 + g], 0, 0, 0);
                }
#pragma unroll
            for (int f = 0; f < 4; f++)
#pragma unroll
                for (int g = 0; g < 2; g++) {
                    acc[4 + f][g] = __builtin_amdgcn_mfma_f32_16x16x32_f16(b0[g][0], a1[f][0], acc[4 + f][g], 0, 0, 0);
                    acc[4 + f][g] = __builtin_amdgcn_mfma_f32_16x16x32_f16(b0[g][1], a1[f][1], acc[4 + f][g], 0, 0, 0);
                }
            __builtin_amdgcn_s_setprio(0);
        } else {
            half8 a0[4][2], a1[4][2], bb[2][2];
#pragma unroll
            for (int f = 0; f < 4; f++) {
                a0[f][0] = *(const half8*)(sAb + rdA0 + f * 1024);
                a0[f][1] = *(const half8*)(sAb + rdA1 + f * 1024);
            }
#pragma unroll
            for (int g = 0; g < 2; g++) {
                bb[g][0] = *(const half8*)(sBb + rdB0 + g * 1024);
                bb[g][1] = *(const half8*)(sBb + rdB1 + g * 1024);
            }
            __builtin_amdgcn_s_setprio(1);
#pragma unroll
            for (int f = 0; f < 4; f++)
#pragma unroll
                for (int g = 0; g < 2; g++) {
                    acc[f][g] = __builtin_amdgcn_mfma_f32_16x16x32_f16(bb[g][0], a0[f][0], acc[f][g], 0, 0, 0);
                    acc[f][g] = __builtin_amdgcn_mfma_f32_16x16x32_f16(bb[g][1], a0[f][1], acc[f][g], 0, 0, 0);
                }
#pragma unroll
            for (int f = 0; f < 4; f++) {
                a1[f][0] = *(const half8*)(sAb + rdA0 + (4 + f) * 1024);
                a1[f][1] = *(const half8*)(sAb + rdA1 + (4 + f) * 1024);
            }
#pragma unroll
            for (int f = 0; f < 4; f++)
#pragma unroll
                for (int g = 0; g < 2; g++) {
                    acc[4 + f][g] = __builtin_amdgcn_mfma_f32_16x16x32_f16(bb[g][0], a1[f][0], acc[4 + f][g], 0, 0, 0);
                    acc[4 + f][g] = __builtin_amdgcn_mfma_f32_16x16x32_f16(bb[g][1], a1[f][1], acc[4 + f][g], 0, 0, 0);
                }
            __builtin_amdgcn_s_setprio(0);
        }

        if (t + 1 < KT) {
            asm volatile("s_waitcnt vmcnt(0)" ::: "memory");
            __builtin_amdgcn_s_barrier();
            __builtin_amdgcn_sched_barrier(0);
        }
    }

    const int rowb = tm * 256 + wm * 128 + cl;
    const int colb = tn * BN + wn * Wn + q * 4;
#pragma unroll
    for (int f = 0; f < 8; f++) {
        size_t ro = (size_t)(rowb + f * 16) * 1024;
#pragma unroll
        for (int g = 0; g < NF; g++) {
            int nb = colb + g * 16;
            f32x4 v = acc[f][g];
            if (EPI == 0) {
                half4 hv;
                hv[0] = (f16)v[0]; hv[1] = (f16)v[1]; hv[2] = (f16)v[2]; hv[3] = (f16)v[3];
                if (nb < 1024) *(half4*)((f16*)C0 + ro + nb) = hv;
                else           *(half4*)((f16*)C1 + ro + nb - 1024) = hv;
            } else {
                *(f32x4*)((float*)C0 + ro + nb) = v;
            }
        }
    }
}

// rule-19 insurance: keep the round-11 instantiation set compiled.
template __global__ void gemm1b<256, 0>(const f16*, int, const f16*, int,
                                        void*, void*, int);

// ---- fp16 GEMM (B^T), m97-style 128x128 - small GEMM (x_proj) --------------
template <int EPI, int AF32>
__global__ __launch_bounds__(256) void gemm_f16(const void* __restrict__ Ap, int lda,
                                                const f16* __restrict__ Bm, int ldb,
                                                void* __restrict__ C0, void* __restrict__ C1,
                                                int ldc, int N, int klen,
                                                const float* __restrict__ fbias) {
    __shared__ alignas(16) f16 sA[128 * 64];
    __shared__ alignas(16) f16 sB[128 * 64];
    const int tid = threadIdx.x;
    const int wave = tid >> 6, lane = tid & 63;
    const int wm = (wave >> 1) * 64, wn = (wave & 1) * 64;
    const int tm = blockIdx.x, tn = blockIdx.y;
    const int q = lane >> 4, cl = lane & 15;
    const int kbeg = blockIdx.z * klen;

    f32x4 acc[4][4];
    const f32x4 zero4 = {0.f, 0.f, 0.f, 0.f};
#pragma unroll
    for (int t = 0; t < 4; t++)
#pragma unroll
        for (int u = 0; u < 4; u++) acc[t][u] = zero4;

    int rS[4], gkS[4];
#pragma unroll
    for (int j = 0; j < 4; j++) {
        int c = wave * 256 + j * 64 + lane;
        rS[j] = c >> 3;
        gkS[j] = (c & 7) ^ (rS[j] & 7);
    }

    for (int k0 = kbeg; k0 < kbeg + klen; k0 += 64) {
        __syncthreads();
#pragma unroll
        for (int j = 0; j < 4; j++) {
            int ldsoff = (wave * 256 + j * 64) * 8;
            if (!AF32) {
                int ga = tm * 128 + rS[j];
                gload_lds16((const f16*)Ap + (size_t)ga * lda + k0 + gkS[j] * 8, sA + ldsoff);
            }
            int gb = tn * 128 + rS[j];
            if (gb >= N) gb = N - 1;
            gload_lds16(Bm + (size_t)gb * ldb + k0 + gkS[j] * 8, sB + ldsoff);
        }
        __syncthreads();

        half8 af[4][2], bf[4][2];
#pragma unroll
        for (int t = 0; t < 4; t++)
#pragma unroll
            for (int s = 0; s < 2; s++) {
                int m = wm + t * 16 + cl;
                int kc = s * 4 + q;
                if (AF32) {
                    const float* pa = (const float*)Ap + (size_t)(tm * 128 + m) * lda + k0 + kc * 8;
                    f32x4 v0 = *(const f32x4*)pa, v1 = *(const f32x4*)(pa + 4);
                    half8 a;
                    a[0] = (f16)v0[0]; a[1] = (f16)v0[1]; a[2] = (f16)v0[2]; a[3] = (f16)v0[3];
                    a[4] = (f16)v1[0]; a[5] = (f16)v1[1]; a[6] = (f16)v1[2]; a[7] = (f16)v1[3];
                    af[t][s] = a;
                } else {
                    af[t][s] = *(const half8*)(sA + m * 64 + ((kc ^ (m & 7)) << 3));
                }
                int n = wn + t * 16 + cl;
                bf[t][s] = *(const half8*)(sB + n * 64 + ((kc ^ (n & 7)) << 3));
            }
#pragma unroll
        for (int t = 0; t < 4; t++)
#pragma unroll
            for (int u = 0; u < 4; u++) {
                acc[t][u] = __builtin_amdgcn_mfma_f32_16x16x32_f16(af[t][0], bf[u][0], acc[t][u], 0, 0, 0);
                acc[t][u] = __builtin_amdgcn_mfma_f32_16x16x32_f16(af[t][1], bf[u][1], acc[t][u], 0, 0, 0);
            }
    }

    const int rowbase = tm * 128 + wm + q * 4;
    const int colbase = tn * 128 + wn + cl;
#pragma unroll
    for (int t = 0; t < 4; t++)
#pragma unroll
        for (int r = 0; r < 4; r++) {
            size_t rb_ = (size_t)(rowbase + t * 16 + r) * ldc;
            size_t rb1 = (size_t)(rowbase + t * 16 + r) * 1024;
#pragma unroll
            for (int u = 0; u < 4; u++) {
                int gcol = colbase + u * 16;
                float v = acc[t][u][r];
                if (EPI == 0) {
                    if (gcol < 1024) ((f16*)C0)[rb1 + gcol] = (f16)v;
                    else             ((f16*)C1)[rb1 + gcol - 1024] = (f16)v;
                } else if (EPI == 1) {
                    if (gcol < N) ((float*)C0)[rb_ + gcol] = v;
                } else if (EPI == 2) {
                    if (gcol < N) atomicAdd((float*)C0 + rb_ + gcol, v);
                } else {
                    if (gcol < N) {
                        float sv = v + fbias[gcol];
                        sv = (sv > 15.f) ? sv : log1pf(__expf(sv));
                        ((f16*)C0)[rb_ + gcol] = (f16)sv;
                    }
                }
            }
        }
}

template __global__ void gemm_f16<3, 1>(const void*, int, const f16*, int,
                                        void*, void*, int, int, int, const float*);
template __global__ void gemm_f16<0, 0>(const void*, int, const f16*, int,
                                        void*, void*, int, int, int, const float*);
template __global__ void gemm_f16<1, 0>(const void*, int, const f16*, int,
                                        void*, void*, int, int, int, const float*);

// ---- dedicated dt_proj: dth[8192,1024] = softplus(dbl[:, :64] @ wdh^T + b) ----
__global__ __launch_bounds__(256) void dtproj_kernel(const float* __restrict__ Ap,
                                                     const f16* __restrict__ Wt,
                                                     f16* __restrict__ Cd,
                                                     const float* __restrict__ fbias) {
    __shared__ alignas(16) f16 sW[128 * 64];
    const int tid = threadIdx.x;
    const int wave = tid >> 6, lane = tid & 63;
    const int q = lane >> 4, cl = lane & 15;
    const int tm = blockIdx.x, tn = blockIdx.y;

#pragma unroll
    for (int j = 0; j < 4; j++) {
        int c = wave * 256 + j * 64 + lane;
        int row = c >> 3;
        int kc = (c & 7) ^ (row & 7);
        gload_lds16(Wt + (size_t)(tn * 128 + row) * 64 + kc * 8,
                    sW + (wave * 256 + j * 64) * 8);
    }

    half8 af[2][2];
#pragma unroll
    for (int t = 0; t < 2; t++)
#pragma unroll
        for (int s = 0; s < 2; s++) {
            int m = wave * 32 + t * 16 + cl;
            const float* pa = Ap + (size_t)(tm * 128 + m) * 80 + (s * 4 + q) * 8;
            f32x4 v0 = *(const f32x4*)pa, v1 = *(const f32x4*)(pa + 4);
            half8 a;
            a[0] = (f16)v0[0]; a[1] = (f16)v0[1]; a[2] = (f16)v0[2]; a[3] = (f16)v0[3];
            a[4] = (f16)v1[0]; a[5] = (f16)v1[1]; a[6] = (f16)v1[2]; a[7] = (f16)v1[3];
            af[t][s] = a;
        }

    __syncthreads();

    f32x4 acc[2][8];
    const f32x4 zero4 = {0.f, 0.f, 0.f, 0.f};
#pragma unroll
    for (int t = 0; t < 2; t++)
#pragma unroll
        for (int fn = 0; fn < 8; fn++) acc[t][fn] = zero4;

#pragma unroll
    for (int fn = 0; fn < 8; fn++) {
        int n = fn * 16 + cl;
#pragma unroll
        for (int s = 0; s < 2; s++) {
            half8 bf = *(const half8*)(sW + n * 64 + (((s * 4 + q) ^ (n & 7)) << 3));
            acc[0][fn] = __builtin_amdgcn_mfma_f32_16x16x32_f16(bf, af[0][s], acc[0][fn], 0, 0, 0);
            acc[1][fn] = __builtin_amdgcn_mfma_f32_16x16x32_f16(bf, af[1][s], acc[1][fn], 0, 0, 0);
        }
    }

    const int rowb = tm * 128 + wave * 32 + cl;
    const int colb = tn * 128 + q * 4;
#pragma unroll
    for (int t = 0; t < 2; t++) {
        size_t ro = (size_t)(rowb + t * 16) * 1024;
#pragma unroll
        for (int fn = 0; fn < 8; fn++) {
            int nb = colb + fn * 16;
            f32x4 v = acc[t][fn];
            half4 hv;
#pragma unroll
            for (int r = 0; r < 4; r++) {
                float sv = v[r] + fbias[nb + r];
                sv = (sv > 15.f) ? sv : log1pf(__expf(sv));
                hv[r] = (f16)sv;
            }
            *(half4*)(Cd + ro + nb) = hv;
        }
    }
}

// ------- causal depthwise conv (K=4) + bias + silu, 4 rows x 4 d / thread ---
__global__ __launch_bounds__(256) void conv_silu_kernel(const f16* __restrict__ x,
                                                        const float* __restrict__ cw,
                                                        const float* __restrict__ cb,
                                                        f16* __restrict__ xc) {
    const int rg = blockIdx.x;
    const int d0 = threadIdx.x * 4;
    const int row0 = rg * 4;
    const int l0 = row0 & (LSEQ - 1);
    f32x4 w[4]; float bias[4];
#pragma unroll
    for (int u = 0; u < 4; u++) {
        w[u] = *(const f32x4*)(cw + (d0 + u) * 4);
        bias[u] = cb[d0 + u];
    }
    float v[7][4];
#pragma unroll
    for (int j = 0; j < 7; j++) {
        int ll = l0 - 3 + j;
        if (ll >= 0) {
            half4 hv = *(const half4*)(x + (size_t)(row0 - 3 + j) * 1024 + d0);
#pragma unroll
            for (int u = 0; u < 4; u++) v[j][u] = (float)hv[u];
        } else {
#pragma unroll
            for (int u = 0; u < 4; u++) v[j][u] = 0.f;
        }
    }
#pragma unroll
    for (int i = 0; i < 4; i++) {
        half4 o;
#pragma unroll
        for (int u = 0; u < 4; u++) {
            float acc = bias[u] + w[u][0] * v[i][u] + w[u][1] * v[i + 1][u]
                      + w[u][2] * v[i + 2][u] + w[u][3] * v[i + 3][u];
            o[u] = (f16)(acc / (1.f + __expf(-acc)));
        }
        *(half4*)(xc + (size_t)(row0 + i) * 1024 + d0) = o;
    }
}

// ---------------- selective scan: 64 chunks of 32, chunk-major state --------
__global__ __launch_bounds__(256) void scan1_kernel(const f16* __restrict__ dt,
                                                    const f16* __restrict__ xc,
                                                    const float* __restrict__ dbl,
                                                    const float* __restrict__ A_log,
                                                    float* __restrict__ hF,
                                                    float* __restrict__ Pb) {
    const int d = blockIdx.x * 256 + threadIdx.x;
    const int c = blockIdx.y;
    const int b = blockIdx.z;
    __shared__ float sB[CHUNKL * NSTATE];   // 256 floats
    sB[threadIdx.x] = dbl[(size_t)(b * LSEQ + c * CHUNKL + (threadIdx.x >> 3)) * 80 + 64 + (threadIdx.x & 7)];
    __syncthreads();
    f32x4 al0 = *(const f32x4*)(A_log + d * 8);
    f32x4 al1 = *(const f32x4*)(A_log + d * 8 + 4);
    float Aa[NSTATE];
#pragma unroll
    for (int n = 0; n < 4; n++) { Aa[n] = -__expf(al0[n]); Aa[n + 4] = -__expf(al1[n]); }
    float h[NSTATE], P[NSTATE];
#pragma unroll
    for (int n = 0; n < NSTATE; n++) { h[n] = 0.f; P[n] = 1.f; }
    const f16* pdt = dt + (size_t)(b * LSEQ + c * CHUNKL) * 1024 + d;
    const f16* pxc = xc + (size_t)(b * LSEQ + c * CHUNKL) * 1024 + d;
    for (int lb = 0; lb < CHUNKL; lb += 8) {
        float vdt[8], vxc[8];
#pragma unroll
        for (int j = 0; j < 8; j++) {
            vdt[j] = (float)pdt[(size_t)(lb + j) * 1024];
            vxc[j] = (float)pxc[(size_t)(lb + j) * 1024];
        }
#pragma unroll
        for (int j = 0; j < 8; j++) {
            float dtx = vdt[j] * vxc[j];
#pragma unroll
            for (int n = 0; n < NSTATE; n++) {
                float e = __expf(Aa[n] * vdt[j]);
                h[n] = e * h[n] + dtx * sB[(lb + j) * 8 + n];
                P[n] *= e;
            }
        }
    }
    size_t base = ((size_t)(c * 4 + b) * 1024 + d) * 8;
    f32x4 o;
    o[0]=h[0]; o[1]=h[1]; o[2]=h[2]; o[3]=h[3]; *(f32x4*)(hF + base) = o;
    o[0]=h[4]; o[1]=h[5]; o[2]=h[6]; o[3]=h[7]; *(f32x4*)(hF + base + 4) = o;
    o[0]=P[0]; o[1]=P[1]; o[2]=P[2]; o[3]=P[3]; *(f32x4*)(Pb + base) = o;
    o[0]=P[4]; o[1]=P[5]; o[2]=P[6]; o[3]=P[7]; *(f32x4*)(Pb + base + 4) = o;
}

// prefix combine over chunks: thread per (b,d,n), coalesced per c-step
__global__ __launch_bounds__(256) void combine_kernel(const float* __restrict__ hF,
                                                      const float* __restrict__ Pb,
                                                      float* __restrict__ h0) {
    int t = blockIdx.x * 256 + threadIdx.x;   // 32768 = 4b*1024d*8n
    int n = t & 7, dd = (t >> 3) & 1023, b = t >> 13;
    size_t off = (size_t)(b * 1024 + dd) * 8 + n;
    float h = 0.f;
#pragma unroll 8
    for (int c = 0; c < NCHUNK; c++) {
        size_t idx = (size_t)c * 32768 + off;
        h0[idx] = h;
        h = fmaf(Pb[idx], h, hF[idx]);
    }
}

__global__ __launch_bounds__(256) void scan2_kernel(const f16* __restrict__ dt,
                                                    const f16* __restrict__ xc,
                                                    const float* __restrict__ dbl,
                                                    const float* __restrict__ A_log,
                                                    const float* __restrict__ h0,
                                                    const f16* __restrict__ z,
                                                    const float* __restrict__ Dsk,
                                                    f16* __restrict__ yout) {
    const int d = blockIdx.x * 256 + threadIdx.x;
    const int c = blockIdx.y;
    const int b = blockIdx.z;
    __shared__ float sB[CHUNKL * NSTATE];
    __shared__ float sC[CHUNKL * NSTATE];
    {
        size_t rb = (size_t)(b * LSEQ + c * CHUNKL + (threadIdx.x >> 3)) * 80;
        sB[threadIdx.x] = dbl[rb + 64 + (threadIdx.x & 7)];
        sC[threadIdx.x] = dbl[rb + 72 + (threadIdx.x & 7)];
    }
    __syncthreads();
    f32x4 al0 = *(const f32x4*)(A_log + d * 8);
    f32x4 al1 = *(const f32x4*)(A_log + d * 8 + 4);
    float Aa[NSTATE];
#pragma unroll
    for (int n = 0; n < 4; n++) { Aa[n] = -__expf(al0[n]); Aa[n + 4] = -__expf(al1[n]); }
    float h[NSTATE];
    {
        size_t base = ((size_t)(c * 4 + b) * 1024 + d) * 8;
        f32x4 h0a = *(const f32x4*)(h0 + base);
        f32x4 h0b = *(const f32x4*)(h0 + base + 4);
#pragma unroll
        for (int n = 0; n < 4; n++) { h[n] = h0a[n]; h[n + 4] = h0b[n]; }
    }
    const float dval = Dsk[d];
    const size_t rowoff = (size_t)(b * LSEQ + c * CHUNKL) * 1024 + d;
    const f16* pdt = dt + rowoff;
    const f16* pxc = xc + rowoff;
    const f16* pz  = z  + rowoff;
    f16* py = yout + rowoff;
    for (int lb = 0; lb < CHUNKL; lb += 8) {
        float vdt[8], vxc[8], vz[8];
#pragma unroll
        for (int j = 0; j < 8; j++) {
            vdt[j] = (float)pdt[(size_t)(lb + j) * 1024];
            vxc[j] = (float)pxc[(size_t)(lb + j) * 1024];
            vz[j]  = (float)pz[(size_t)(lb + j) * 1024];
        }
#pragma unroll
        for (int j = 0; j < 8; j++) {
            float dtx = vdt[j] * vxc[j];
            float y = 0.f;
#pragma unroll
            for (int n = 0; n < NSTATE; n++) {
                float e = __expf(Aa[n] * vdt[j]);
                h[n] = e * h[n] + dtx * sB[(lb + j) * 8 + n];
                y += h[n] * sC[(lb + j) * 8 + n];
            }
            y += dval * vxc[j];
            y *= vz[j] / (1.f + __expf(-vz[j]));
            py[(size_t)(lb + j) * 1024] = (f16)y;
        }
    }
}

extern "C" void kernel_launch(void* const* d_in, const int* in_sizes, int n_in,
                              void* d_out, int out_size, void* d_ws, size_t ws_size,
                              hipStream_t stream) {
    (void)in_sizes; (void)n_in;
    const float* hidden    = (const float*)d_in[0];
    const float* norm_w    = (const float*)d_in[1];
    const float* in_proj_w = (const float*)d_in[2];
    const float* conv_w    = (const float*)d_in[3];
    const float* conv_b    = (const float*)d_in[4];
    const float* x_proj_w  = (const float*)d_in[5];
    const float* dt_proj_w = (const float*)d_in[6];
    const float* dt_proj_b = (const float*)d_in[7];
    const float* A_log     = (const float*)d_in[8];
    const float* D_skip    = (const float*)d_in[9];
    const float* out_proj_w= (const float*)d_in[10];
    float* out = (float*)d_out;

    if (ws_size < WS_NEED) {
        sentinel_kernel<<<dim3((out_size + 255) / 256), 256, 0, stream>>>(out, out_size);
        return;
    }

    char* ws = (char*)d_ws;
    f16*   xn_h  = (f16*)(ws);                         // [0,16) -> y_h later
    f16*   xbuf_h= (f16*)(ws + (16ull << 20));         // [16,32)
    f16*   zbuf_h= (f16*)(ws + (32ull << 20));         // [32,48)
    f16*   xc_h  = (f16*)(ws + (48ull << 20));         // [48,64)
    f16*   wih   = (f16*)(ws + (64ull << 20));         // [64,68)
    f16*   woh   = (f16*)(ws + (68ull << 20));         // [68,70)
    f16*   wxh   = (f16*)(ws + (70ull << 20));         // 160 KB
    f16*   wdh   = (f16*)(ws + (70ull << 20) + (512ull << 10));  // 128 KB
    float* dbl_f = (float*)(ws + (71ull << 20));       // 2.5 MB
    f16*   dth   = (f16*)(ws + (75ull << 20));         // [75,91)
    float* hF    = (float*)(ws + (91ull << 20));       // 8 MB
    float* Pb    = (float*)(ws + (99ull << 20));       // 8 MB
    float* h0    = (float*)(ws + (107ull << 20));      // 8 MB
    f16*   y_h   = xn_h;

    prep_kernel<<<dim3(WCVT_BLK + ZERO_BLK + NROWS), 256, 0, stream>>>(
        in_proj_w, x_proj_w, dt_proj_w, out_proj_w, wih, wxh, wdh, woh,
        dbl_f, hidden, norm_w, xn_h);
    // in_proj: M=8192 N=2048 K=1024 -> 128x256 tiles, grid (64,8)=512 (2/CU), KT=32
    gemm128<<<dim3(64, 8), 512, 0, stream>>>(xn_h, 1024, wih, 1024,
                                             xbuf_h, zbuf_h, 32);
    conv_silu_kernel<<<dim3(NROWS / 4), 256, 0, stream>>>(xbuf_h, conv_w, conv_b, xc_h);
    gemm_f16<2, 0><<<dim3(64, 1, 4), 256, 0, stream>>>(xc_h, 1024, wxh, 1024,
                                                       dbl_f, nullptr, 80, 80, 256, nullptr);
    dtproj_kernel<<<dim3(64, 8), 256, 0, stream>>>(dbl_f, wdh, dth, dt_proj_b);
    scan1_kernel<<<dim3(4, NCHUNK, 4), 256, 0, stream>>>(dth, xc_h, dbl_f, A_log, hF, Pb);
    combine_kernel<<<dim3(128), 256, 0, stream>>>(hF, Pb, h0);
    scan2_kernel<<<dim3(4, NCHUNK, 4), 256, 0, stream>>>(dth, xc_h, dbl_f, A_log, h0,
                                                         zbuf_h, D_skip, y_h);
    // out_proj: M=8192 N=1024 K=1024 -> 256x128 tiles, grid (32,8)=256
    gemm1b<128, 1><<<dim3(32, 8), 512, 0, stream>>>(y_h, 1024, woh, 1024,
                                                    out, nullptr, 16);
}

// Round 13
// 283.237 us; speedup vs baseline: 1.2183x; 1.2183x over previous
//
#include <hip/hip_runtime.h>
#include <stdint.h>
#include <stddef.h>

// Mamba block, B=4 L=2048 D=DI=1024 N=8 K=4 R=64. I/O fp32; GEMMs fp16 MFMA.
// Round 13: FULL REVERT to the round-6 configuration (best measured total:
// 283.7us). Rationale: R10-R12's gemm128 occupancy/bank-conflict branch
// produced zero net gain and two failure modes (R10/R11: 4.19M bank conflicts
// under two different swizzles; R12: source-identical dtproj collapsed to
// 117us / MfmaUtil 0.35% - rule-19-style cross-kernel codegen perturbation or
// a degraded machine). Reverting re-anchors the baseline and isolates R12's
// dtproj pathology: known-good source -> ~284 means build-linked; still-slow
// dtproj means environment.
// Config (= round 6): in_proj gemm1b<0> (256x256, BK=64, 8 waves, free-form
// single-barrier counted K-loop, 0-conflict XOR swizzle); x_proj gemm_f16<2,0>;
// dtproj dedicated kernel; out_proj gemm_f16<1,0>; scalar epilogues.
// Dispatches: prep -> in_proj(gemm1b) -> conv -> x_proj -> dtproj -> scan1
//   -> combine -> scan2 -> out_proj.  ws layout unchanged (115 MiB).

typedef unsigned short u16;
typedef unsigned int u32;
typedef _Float16 f16;
typedef __attribute__((ext_vector_type(8))) _Float16 half8;
typedef __attribute__((ext_vector_type(4))) _Float16 half4;
typedef __attribute__((ext_vector_type(4))) float f32x4;

#define LSEQ 2048
#define DMODEL 1024
#define NSTATE 8
#define NCHUNK 64
#define CHUNKL 32
#define NROWS 8192
#define WS_NEED (115ull << 20)

__device__ __forceinline__ void gload_lds16(const void* g, void* l) {
    __builtin_amdgcn_global_load_lds((__attribute__((address_space(1))) void*)g,
                                     (__attribute__((address_space(3))) void*)l,
                                     16, 0, 0);
}

__global__ __launch_bounds__(256) void sentinel_kernel(float* __restrict__ out, int n) {
    int i = blockIdx.x * 256 + threadIdx.x;
    if (i < n) out[i] = 999.0f;
}

// ---- prep: weight fp32->fp16 (4 tensors) + zero dbl_f + rmsnorm ----
#define T0 524288   // in_proj_w /4
#define T1 20480    // x_proj_w /4
#define T2 16384    // dt_proj_w /4
#define T3 262144   // out_proj_w /4
#define WCVT_BLK 3216          // (T0+T1+T2+T3)/256
#define ZERO_BLK 640           // 8192*80*4B / 16B / 256
__global__ __launch_bounds__(256) void prep_kernel(const float* __restrict__ s0,
                                                   const float* __restrict__ s1,
                                                   const float* __restrict__ s2,
                                                   const float* __restrict__ s3,
                                                   f16* __restrict__ d0, f16* __restrict__ d1,
                                                   f16* __restrict__ d2, f16* __restrict__ d3,
                                                   float* __restrict__ dblz,
                                                   const float* __restrict__ X,
                                                   const float* __restrict__ W,
                                                   f16* __restrict__ O) {
    const int bx = blockIdx.x;
    const int tid = threadIdx.x;
    if (bx < WCVT_BLK) {
        int idx = bx * 256 + tid;
        const float* s; f16* d; int i;
        if (idx < T0) { s = s0; d = d0; i = idx; }
        else if (idx < T0 + T1) { s = s1; d = d1; i = idx - T0; }
        else if (idx < T0 + T1 + T2) { s = s2; d = d2; i = idx - T0 - T1; }
        else { s = s3; d = d3; i = idx - T0 - T1 - T2; }
        f32x4 v = *(const f32x4*)(s + (size_t)i * 4);
        half4 o; o[0] = (f16)v[0]; o[1] = (f16)v[1]; o[2] = (f16)v[2]; o[3] = (f16)v[3];
        *(half4*)(d + (size_t)i * 4) = o;
    } else if (bx < WCVT_BLK + ZERO_BLK) {
        int i = (bx - WCVT_BLK) * 256 + tid;
        const f32x4 z4 = {0.f, 0.f, 0.f, 0.f};
        ((f32x4*)dblz)[i] = z4;
    } else {
        const int row = bx - (WCVT_BLK + ZERO_BLK);
        f32x4 u = *(const f32x4*)(X + (size_t)row * DMODEL + tid * 4);
        float ss = u[0]*u[0] + u[1]*u[1] + u[2]*u[2] + u[3]*u[3];
        for (int off = 32; off; off >>= 1) ss += __shfl_down(ss, off, 64);
        __shared__ float red[4];
        if ((tid & 63) == 0) red[tid >> 6] = ss;
        __syncthreads();
        float tot = red[0] + red[1] + red[2] + red[3];
        float scale = rsqrtf(tot * (1.0f / DMODEL) + 1e-5f);
        f32x4 w = *(const f32x4*)(W + tid * 4);
        half4 o;
        o[0] = (f16)(u[0] * scale * w[0]); o[1] = (f16)(u[1] * scale * w[1]);
        o[2] = (f16)(u[2] * scale * w[2]); o[3] = (f16)(u[3] * scale * w[3]);
        *(half4*)(O + (size_t)row * DMODEL + tid * 4) = o;
    }
}

// ============== one-barrier-per-K-tile counted 256x256 GEMM (in_proj) =======
// C[m,n] = sum_k A[m,k]*Bm[n,k]. 512 thr (8 waves, 2M x 4N), BK=64 per K-tile.
// LDS 2 x [256 rows][8 slots of 16B] per matrix; slot kc holds global kchunk
// kc^(row&7) (pre-swizzled global source, linear gload_lds dest; 0-conflict).
// EPI 0: split fp16 store (col<1024 -> C0 else C1). EPI 1: fp32 store.

#define SA8(tt, hf) do { \
    gload_lds16(aG + (size_t)(tt) * 64 + (size_t)(hf) * hA, \
                sA + (((tt) & 1) * 16384) + (hf) * 8192 + ldsW); \
    gload_lds16(aG + (size_t)(tt) * 64 + (size_t)(hf) * hA + rA, \
                sA + (((tt) & 1) * 16384) + (hf) * 8192 + 4096 + ldsW); \
} while (0)
#define SB8(tt, hf) do { \
    gload_lds16(bG + (size_t)(tt) * 64 + (size_t)(hf) * hB, \
                sB + (((tt) & 1) * 16384) + (hf) * 8192 + ldsW); \
    gload_lds16(bG + (size_t)(tt) * 64 + (size_t)(hf) * hB + rB, \
                sB + (((tt) & 1) * 16384) + (hf) * 8192 + 4096 + ldsW); \
} while (0)

template <int EPI>
__global__ __launch_bounds__(512, 2) void gemm1b(const f16* __restrict__ Ap, int lda,
                                                 const f16* __restrict__ Bm, int ldb,
                                                 void* __restrict__ C0, void* __restrict__ C1,
                                                 int KT) {
    __shared__ alignas(16) f16 sA[2 * 256 * 64];   // 64 KiB
    __shared__ alignas(16) f16 sB[2 * 256 * 64];   // 64 KiB
    const int tid = threadIdx.x;
    const int wave = tid >> 6, lane = tid & 63;
    const int wm = wave >> 2, wn = wave & 3;       // 2M x 4N waves
    const int cl = lane & 15, q = lane >> 4;
    const int tm = blockIdx.x, tn = blockIdx.y;

    // staging: tid -> row=tid>>3, slot=tid&7; global kc = slot ^ (row&7).
    const int srow = tid >> 3;
    const int skc = (tid & 7) ^ (srow & 7);
    const f16* aG = Ap + (size_t)(tm * 256 + srow) * lda + skc * 8;
    const f16* bG = Bm + (size_t)(tn * 256 + srow) * ldb + skc * 8;
    const size_t rA = (size_t)64 * lda, hA = (size_t)128 * lda;
    const size_t rB = (size_t)64 * ldb, hB = (size_t)128 * ldb;
    const int ldsW = wave * 512;                   // f16 elems: wave's 64x16B slice

    // per-lane ds_read bases (frag row = 16*f + cl => row&7 == cl&7)
    const int swz0 = (q ^ (cl & 7)) << 3;
    const int swz1 = ((4 + q) ^ (cl & 7)) << 3;
    const int rdA0 = (wm * 128 + cl) * 64 + swz0;
    const int rdA1 = (wm * 128 + cl) * 64 + swz1;
    const int rdB0 = (wn * 64 + cl) * 64 + swz0;
    const int rdB1 = (wn * 64 + cl) * 64 + swz1;

    f32x4 acc[8][4];
    const f32x4 zero4 = {0.f, 0.f, 0.f, 0.f};
#pragma unroll
    for (int f = 0; f < 8; f++)
#pragma unroll
        for (int g = 0; g < 4; g++) acc[f][g] = zero4;

    // prologue: stage tile 0, drain once, rendezvous.
    SA8(0, 0); SA8(0, 1); SB8(0, 0); SB8(0, 1);
    asm volatile("s_waitcnt vmcnt(0)" ::: "memory");
    __builtin_amdgcn_s_barrier();
    __builtin_amdgcn_sched_barrier(0);

    for (int t = 0; t < KT; t++) {
        const f16* sAb = sA + (t & 1) * 16384;
        const f16* sBb = sB + (t & 1) * 16384;

        // issue next tile's staging first: full-tile latency coverage.
        if (t + 1 < KT) { SA8(t + 1, 0); SA8(t + 1, 1); SB8(t + 1, 0); SB8(t + 1, 1); }
        __builtin_amdgcn_sched_barrier(0);

        // operand halves read ONCE each; compiler schedules ds_read/lgkm/MFMA.
        half8 a0[4][2], a1[4][2], b0[2][2], b1[2][2];
#pragma unroll
        for (int f = 0; f < 4; f++) {
            a0[f][0] = *(const half8*)(sAb + rdA0 + f * 1024);
            a0[f][1] = *(const half8*)(sAb + rdA1 + f * 1024);
        }
#pragma unroll
        for (int g = 0; g < 2; g++) {
            b0[g][0] = *(const half8*)(sBb + rdB0 + g * 1024);
            b0[g][1] = *(const half8*)(sBb + rdB1 + g * 1024);
        }
        __builtin_amdgcn_s_setprio(1);
#pragma unroll
        for (int f = 0; f < 4; f++)
#pragma unroll
            for (int g = 0; g < 2; g++) {
                acc[f][g] = __builtin_amdgcn_mfma_f32_16x16x32_f16(a0[f][0], b0[g][0], acc[f][g], 0, 0, 0);
                acc[f][g] = __builtin_amdgcn_mfma_f32_16x16x32_f16(a0[f][1], b0[g][1], acc[f][g], 0, 0, 0);
            }
#pragma unroll
        for (int g = 0; g < 2; g++) {
            b1[g][0] = *(const half8*)(sBb + rdB0 + (2 + g) * 1024);
            b1[g][1] = *(const half8*)(sBb + rdB1 + (2 + g) * 1024);
        }
#pragma unroll
        for (int f = 0; f < 4; f++)
#pragma unroll
            for (int g = 0; g < 2; g++) {
                acc[f][2 + g] = __builtin_amdgcn_mfma_f32_16x16x32_f16(a0[f][0], b1[g][0], acc[f][2 + g], 0, 0, 0);
                acc[f][2 + g] = __builtin_amdgcn_mfma_f32_16x16x32_f16(a0[f][1], b1[g][1], acc[f][2 + g], 0, 0, 0);
            }
#pragma unroll
        for (int f = 0; f < 4; f++) {
            a1[f][0] = *(const half8*)(sAb + rdA0 + (4 + f) * 1024);
            a1[f][1] = *(const half8*)(sAb + rdA1 + (4 + f) * 1024);
        }
#pragma unroll
        for (int f = 0; f < 4; f++)
#pragma unroll
            for (int g = 0; g < 2; g++) {
                acc[4 + f][2 + g] = __builtin_amdgcn_mfma_f32_16x16x32_f16(a1[f][0], b1[g][0], acc[4 + f][2 + g], 0, 0, 0);
                acc[4 + f][2 + g] = __builtin_amdgcn_mfma_f32_16x16x32_f16(a1[f][1], b1[g][1], acc[4 + f][2 + g], 0, 0, 0);
            }
#pragma unroll
        for (int f = 0; f < 4; f++)
#pragma unroll
            for (int g = 0; g < 2; g++) {
                acc[4 + f][g] = __builtin_amdgcn_mfma_f32_16x16x32_f16(a1[f][0], b0[g][0], acc[4 + f][g], 0, 0, 0);
                acc[4 + f][g] = __builtin_amdgcn_mfma_f32_16x16x32_f16(a1[f][1], b0[g][1], acc[4 + f][g], 0, 0, 0);
            }
        __builtin_amdgcn_s_setprio(0);

        if (t + 1 < KT) {
            // staging for t+1 was issued one full tile of compute ago -> ~free.
            asm volatile("s_waitcnt vmcnt(0)" ::: "memory");
            __builtin_amdgcn_s_barrier();
            __builtin_amdgcn_sched_barrier(0);
        }
    }

    // epilogue: C/D layout col=lane&15, row=(lane>>4)*4+r
    const int rowb = tm * 256 + wm * 128 + q * 4;
    const int colb = tn * 256 + wn * 64 + cl;
#pragma unroll
    for (int f = 0; f < 8; f++)
#pragma unroll
        for (int r = 0; r < 4; r++) {
            size_t ro = (size_t)(rowb + f * 16 + r) * 1024;
#pragma unroll
            for (int g = 0; g < 4; g++) {
                int gc = colb + g * 16;
                float v = acc[f][g][r];
                if (EPI == 0) {
                    if (gc < 1024) ((f16*)C0)[ro + gc] = (f16)v;
                    else           ((f16*)C1)[ro + gc - 1024] = (f16)v;
                } else {
                    ((float*)C0)[ro + gc] = v;
                }
            }
        }
}

// ---- fp16 GEMM (B^T), m97-style 128x128 - small GEMMs (x_proj, out_proj) ----
template <int EPI, int AF32>
__global__ __launch_bounds__(256) void gemm_f16(const void* __restrict__ Ap, int lda,
                                                const f16* __restrict__ Bm, int ldb,
                                                void* __restrict__ C0, void* __restrict__ C1,
                                                int ldc, int N, int klen,
                                                const float* __restrict__ fbias) {
    __shared__ alignas(16) f16 sA[128 * 64];
    __shared__ alignas(16) f16 sB[128 * 64];
    const int tid = threadIdx.x;
    const int wave = tid >> 6, lane = tid & 63;
    const int wm = (wave >> 1) * 64, wn = (wave & 1) * 64;
    const int tm = blockIdx.x, tn = blockIdx.y;
    const int q = lane >> 4, cl = lane & 15;
    const int kbeg = blockIdx.z * klen;

    f32x4 acc[4][4];
    const f32x4 zero4 = {0.f, 0.f, 0.f, 0.f};
#pragma unroll
    for (int t = 0; t < 4; t++)
#pragma unroll
        for (int u = 0; u < 4; u++) acc[t][u] = zero4;

    int rS[4], gkS[4];
#pragma unroll
    for (int j = 0; j < 4; j++) {
        int c = wave * 256 + j * 64 + lane;
        rS[j] = c >> 3;
        gkS[j] = (c & 7) ^ (rS[j] & 7);
    }

    for (int k0 = kbeg; k0 < kbeg + klen; k0 += 64) {
        __syncthreads();
#pragma unroll
        for (int j = 0; j < 4; j++) {
            int ldsoff = (wave * 256 + j * 64) * 8;
            if (!AF32) {
                int ga = tm * 128 + rS[j];
                gload_lds16((const f16*)Ap + (size_t)ga * lda + k0 + gkS[j] * 8, sA + ldsoff);
            }
            int gb = tn * 128 + rS[j];
            if (gb >= N) gb = N - 1;
            gload_lds16(Bm + (size_t)gb * ldb + k0 + gkS[j] * 8, sB + ldsoff);
        }
        __syncthreads();

        half8 af[4][2], bf[4][2];
#pragma unroll
        for (int t = 0; t < 4; t++)
#pragma unroll
            for (int s = 0; s < 2; s++) {
                int m = wm + t * 16 + cl;
                int kc = s * 4 + q;
                if (AF32) {
                    const float* pa = (const float*)Ap + (size_t)(tm * 128 + m) * lda + k0 + kc * 8;
                    f32x4 v0 = *(const f32x4*)pa, v1 = *(const f32x4*)(pa + 4);
                    half8 a;
                    a[0] = (f16)v0[0]; a[1] = (f16)v0[1]; a[2] = (f16)v0[2]; a[3] = (f16)v0[3];
                    a[4] = (f16)v1[0]; a[5] = (f16)v1[1]; a[6] = (f16)v1[2]; a[7] = (f16)v1[3];
                    af[t][s] = a;
                } else {
                    af[t][s] = *(const half8*)(sA + m * 64 + ((kc ^ (m & 7)) << 3));
                }
                int n = wn + t * 16 + cl;
                bf[t][s] = *(const half8*)(sB + n * 64 + ((kc ^ (n & 7)) << 3));
            }
#pragma unroll
        for (int t = 0; t < 4; t++)
#pragma unroll
            for (int u = 0; u < 4; u++) {
                acc[t][u] = __builtin_amdgcn_mfma_f32_16x16x32_f16(af[t][0], bf[u][0], acc[t][u], 0, 0, 0);
                acc[t][u] = __builtin_amdgcn_mfma_f32_16x16x32_f16(af[t][1], bf[u][1], acc[t][u], 0, 0, 0);
            }
    }

    const int rowbase = tm * 128 + wm + q * 4;
    const int colbase = tn * 128 + wn + cl;
#pragma unroll
    for (int t = 0; t < 4; t++)
#pragma unroll
        for (int r = 0; r < 4; r++) {
            size_t rb_ = (size_t)(rowbase + t * 16 + r) * ldc;
            size_t rb1 = (size_t)(rowbase + t * 16 + r) * 1024;
#pragma unroll
            for (int u = 0; u < 4; u++) {
                int gcol = colbase + u * 16;
                float v = acc[t][u][r];
                if (EPI == 0) {
                    if (gcol < 1024) ((f16*)C0)[rb1 + gcol] = (f16)v;
                    else             ((f16*)C1)[rb1 + gcol - 1024] = (f16)v;
                } else if (EPI == 1) {
                    if (gcol < N) ((float*)C0)[rb_ + gcol] = v;
                } else if (EPI == 2) {
                    if (gcol < N) atomicAdd((float*)C0 + rb_ + gcol, v);
                } else {
                    if (gcol < N) {
                        float sv = v + fbias[gcol];
                        sv = (sv > 15.f) ? sv : log1pf(__expf(sv));
                        ((f16*)C0)[rb_ + gcol] = (f16)sv;
                    }
                }
            }
        }
}

// rule-19 insurance: keep the instantiation set compiled even when not
// launched, so EPI=1/EPI=2 codegen context is unchanged.
template __global__ void gemm_f16<3, 1>(const void*, int, const f16*, int,
                                        void*, void*, int, int, int, const float*);
template __global__ void gemm_f16<0, 0>(const void*, int, const f16*, int,
                                        void*, void*, int, int, int, const float*);

// ---- dedicated dt_proj: dth[8192,1024] = softplus(dbl[:, :64] @ wdh^T + b) ----
__global__ __launch_bounds__(256) void dtproj_kernel(const float* __restrict__ Ap,
                                                     const f16* __restrict__ Wt,
                                                     f16* __restrict__ Cd,
                                                     const float* __restrict__ fbias) {
    __shared__ alignas(16) f16 sW[128 * 64];
    const int tid = threadIdx.x;
    const int wave = tid >> 6, lane = tid & 63;
    const int q = lane >> 4, cl = lane & 15;
    const int tm = blockIdx.x, tn = blockIdx.y;

#pragma unroll
    for (int j = 0; j < 4; j++) {
        int c = wave * 256 + j * 64 + lane;
        int row = c >> 3;
        int kc = (c & 7) ^ (row & 7);
        gload_lds16(Wt + (size_t)(tn * 128 + row) * 64 + kc * 8,
                    sW + (wave * 256 + j * 64) * 8);
    }

    half8 af[2][2];
#pragma unroll
    for (int t = 0; t < 2; t++)
#pragma unroll
        for (int s = 0; s < 2; s++) {
            int m = wave * 32 + t * 16 + cl;
            const float* pa = Ap + (size_t)(tm * 128 + m) * 80 + (s * 4 + q) * 8;
            f32x4 v0 = *(const f32x4*)pa, v1 = *(const f32x4*)(pa + 4);
            half8 a;
            a[0] = (f16)v0[0]; a[1] = (f16)v0[1]; a[2] = (f16)v0[2]; a[3] = (f16)v0[3];
            a[4] = (f16)v1[0]; a[5] = (f16)v1[1]; a[6] = (f16)v1[2]; a[7] = (f16)v1[3];
            af[t][s] = a;
        }

    __syncthreads();

    f32x4 acc[2][8];
    const f32x4 zero4 = {0.f, 0.f, 0.f, 0.f};
#pragma unroll
    for (int t = 0; t < 2; t++)
#pragma unroll
        for (int fn = 0; fn < 8; fn++) acc[t][fn] = zero4;

#pragma unroll
    for (int fn = 0; fn < 8; fn++) {
        int n = fn * 16 + cl;
#pragma unroll
        for (int s = 0; s < 2; s++) {
            half8 bf = *(const half8*)(sW + n * 64 + (((s * 4 + q) ^ (n & 7)) << 3));
            acc[0][fn] = __builtin_amdgcn_mfma_f32_16x16x32_f16(af[0][s], bf, acc[0][fn], 0, 0, 0);
            acc[1][fn] = __builtin_amdgcn_mfma_f32_16x16x32_f16(af[1][s], bf, acc[1][fn], 0, 0, 0);
        }
    }

    const int rowb = tm * 128 + wave * 32 + q * 4;
    const int colb = tn * 128 + cl;
#pragma unroll
    for (int t = 0; t < 2; t++)
#pragma unroll
        for (int r = 0; r < 4; r++) {
            size_t ro = (size_t)(rowb + t * 16 + r) * 1024;
#pragma unroll
            for (int fn = 0; fn < 8; fn++) {
                int gc = colb + fn * 16;
                float sv = acc[t][fn][r] + fbias[gc];
                sv = (sv > 15.f) ? sv : log1pf(__expf(sv));
                Cd[ro + gc] = (f16)sv;
            }
        }
}

// ------- causal depthwise conv (K=4) + bias + silu, 4 rows per thread -------
__global__ __launch_bounds__(256) void conv_silu_kernel(const f16* __restrict__ x,
                                                        const float* __restrict__ cw,
                                                        const float* __restrict__ cb,
                                                        f16* __restrict__ xc) {
    const int rg = blockIdx.x;
    const int d = blockIdx.y * 256 + threadIdx.x;
    const int row0 = rg * 4;
    const int l0 = row0 & (LSEQ - 1);
    float w0 = cw[d * 4], w1 = cw[d * 4 + 1], w2 = cw[d * 4 + 2], w3 = cw[d * 4 + 3];
    float bias = cb[d];
    float v[7];
#pragma unroll
    for (int j = 0; j < 7; j++) {
        int ll = l0 - 3 + j;
        v[j] = (ll >= 0) ? (float)x[(size_t)(row0 - 3 + j) * 1024 + d] : 0.f;
    }
#pragma unroll
    for (int i = 0; i < 4; i++) {
        float acc = bias + w0 * v[i] + w1 * v[i + 1] + w2 * v[i + 2] + w3 * v[i + 3];
        xc[(size_t)(row0 + i) * 1024 + d] = (f16)(acc / (1.f + __expf(-acc)));
    }
}

// ---------------- selective scan: 64 chunks of 32, chunk-major state --------
// state layout: hF/Pb/h0 [c][b][d][n] -> offset ((c*4+b)*1024+d)*8+n
__global__ __launch_bounds__(256) void scan1_kernel(const f16* __restrict__ dt,
                                                    const f16* __restrict__ xc,
                                                    const float* __restrict__ dbl,
                                                    const float* __restrict__ A_log,
                                                    float* __restrict__ hF,
                                                    float* __restrict__ Pb) {
    const int d = blockIdx.x * 256 + threadIdx.x;
    const int c = blockIdx.y;
    const int b = blockIdx.z;
    __shared__ float sB[CHUNKL * NSTATE];   // 256 floats
    sB[threadIdx.x] = dbl[(size_t)(b * LSEQ + c * CHUNKL + (threadIdx.x >> 3)) * 80 + 64 + (threadIdx.x & 7)];
    __syncthreads();
    f32x4 al0 = *(const f32x4*)(A_log + d * 8);
    f32x4 al1 = *(const f32x4*)(A_log + d * 8 + 4);
    float Aa[NSTATE];
#pragma unroll
    for (int n = 0; n < 4; n++) { Aa[n] = -__expf(al0[n]); Aa[n + 4] = -__expf(al1[n]); }
    float h[NSTATE], P[NSTATE];
#pragma unroll
    for (int n = 0; n < NSTATE; n++) { h[n] = 0.f; P[n] = 1.f; }
    const f16* pdt = dt + (size_t)(b * LSEQ + c * CHUNKL) * 1024 + d;
    const f16* pxc = xc + (size_t)(b * LSEQ + c * CHUNKL) * 1024 + d;
    for (int lb = 0; lb < CHUNKL; lb += 8) {
        float vdt[8], vxc[8];
#pragma unroll
        for (int j = 0; j < 8; j++) {
            vdt[j] = (float)pdt[(size_t)(lb + j) * 1024];
            vxc[j] = (float)pxc[(size_t)(lb + j) * 1024];
        }
#pragma unroll
        for (int j = 0; j < 8; j++) {
            float dtx = vdt[j] * vxc[j];
#pragma unroll
            for (int n = 0; n < NSTATE; n++) {
                float e = __expf(Aa[n] * vdt[j]);
                h[n] = e * h[n] + dtx * sB[(lb + j) * 8 + n];
                P[n] *= e;
            }
        }
    }
    size_t base = ((size_t)(c * 4 + b) * 1024 + d) * 8;
    f32x4 o;
    o[0]=h[0]; o[1]=h[1]; o[2]=h[2]; o[3]=h[3]; *(f32x4*)(hF + base) = o;
    o[0]=h[4]; o[1]=h[5]; o[2]=h[6]; o[3]=h[7]; *(f32x4*)(hF + base + 4) = o;
    o[0]=P[0]; o[1]=P[1]; o[2]=P[2]; o[3]=P[3]; *(f32x4*)(Pb + base) = o;
    o[0]=P[4]; o[1]=P[5]; o[2]=P[6]; o[3]=P[7]; *(f32x4*)(Pb + base + 4) = o;
}

// prefix combine over chunks: thread per (b,d,n), coalesced per c-step
__global__ __launch_bounds__(256) void combine_kernel(const float* __restrict__ hF,
                                                      const float* __restrict__ Pb,
                                                      float* __restrict__ h0) {
    int t = blockIdx.x * 256 + threadIdx.x;   // 32768 = 4b*1024d*8n
    int n = t & 7, dd = (t >> 3) & 1023, b = t >> 13;
    size_t off = (size_t)(b * 1024 + dd) * 8 + n;
    float h = 0.f;
#pragma unroll 8
    for (int c = 0; c < NCHUNK; c++) {
        size_t idx = (size_t)c * 32768 + off;
        h0[idx] = h;
        h = fmaf(Pb[idx], h, hF[idx]);
    }
}

__global__ __launch_bounds__(256) void scan2_kernel(const f16* __restrict__ dt,
                                                    const f16* __restrict__ xc,
                                                    const float* __restrict__ dbl,
                                                    const float* __restrict__ A_log,
                                                    const float* __restrict__ h0,
                                                    const f16* __restrict__ z,
                                                    const float* __restrict__ Dsk,
                                                    f16* __restrict__ yout) {
    const int d = blockIdx.x * 256 + threadIdx.x;
    const int c = blockIdx.y;
    const int b = blockIdx.z;
    __shared__ float sB[CHUNKL * NSTATE];
    __shared__ float sC[CHUNKL * NSTATE];
    {
        size_t rb = (size_t)(b * LSEQ + c * CHUNKL + (threadIdx.x >> 3)) * 80;
        sB[threadIdx.x] = dbl[rb + 64 + (threadIdx.x & 7)];
        sC[threadIdx.x] = dbl[rb + 72 + (threadIdx.x & 7)];
    }
    __syncthreads();
    f32x4 al0 = *(const f32x4*)(A_log + d * 8);
    f32x4 al1 = *(const f32x4*)(A_log + d * 8 + 4);
    float Aa[NSTATE];
#pragma unroll
    for (int n = 0; n < 4; n++) { Aa[n] = -__expf(al0[n]); Aa[n + 4] = -__expf(al1[n]); }
    float h[NSTATE];
    {
        size_t base = ((size_t)(c * 4 + b) * 1024 + d) * 8;
        f32x4 h0a = *(const f32x4*)(h0 + base);
        f32x4 h0b = *(const f32x4*)(h0 + base + 4);
#pragma unroll
        for (int n = 0; n < 4; n++) { h[n] = h0a[n]; h[n + 4] = h0b[n]; }
    }
    const float dval = Dsk[d];
    const size_t rowoff = (size_t)(b * LSEQ + c * CHUNKL) * 1024 + d;
    const f16* pdt = dt + rowoff;
    const f16* pxc = xc + rowoff;
    const f16* pz  = z  + rowoff;
    f16* py = yout + rowoff;
    for (int lb = 0; lb < CHUNKL; lb += 8) {
        float vdt[8], vxc[8], vz[8];
#pragma unroll
        for (int j = 0; j < 8; j++) {
            vdt[j] = (float)pdt[(size_t)(lb + j) * 1024];
            vxc[j] = (float)pxc[(size_t)(lb + j) * 1024];
            vz[j]  = (float)pz[(size_t)(lb + j) * 1024];
        }
#pragma unroll
        for (int j = 0; j < 8; j++) {
            float dtx = vdt[j] * vxc[j];
            float y = 0.f;
#pragma unroll
            for (int n = 0; n < NSTATE; n++) {
                float e = __expf(Aa[n] * vdt[j]);
                h[n] = e * h[n] + dtx * sB[(lb + j) * 8 + n];
                y += h[n] * sC[(lb + j) * 8 + n];
            }
            y += dval * vxc[j];
            y *= vz[j] / (1.f + __expf(-vz[j]));
            py[(size_t)(lb + j) * 1024] = (f16)y;
        }
    }
}

extern "C" void kernel_launch(void* const* d_in, const int* in_sizes, int n_in,
                              void* d_out, int out_size, void* d_ws, size_t ws_size,
                              hipStream_t stream) {
    (void)in_sizes; (void)n_in;
    const float* hidden    = (const float*)d_in[0];
    const float* norm_w    = (const float*)d_in[1];
    const float* in_proj_w = (const float*)d_in[2];
    const float* conv_w    = (const float*)d_in[3];
    const float* conv_b    = (const float*)d_in[4];
    const float* x_proj_w  = (const float*)d_in[5];
    const float* dt_proj_w = (const float*)d_in[6];
    const float* dt_proj_b = (const float*)d_in[7];
    const float* A_log     = (const float*)d_in[8];
    const float* D_skip    = (const float*)d_in[9];
    const float* out_proj_w= (const float*)d_in[10];
    float* out = (float*)d_out;

    if (ws_size < WS_NEED) {
        sentinel_kernel<<<dim3((out_size + 255) / 256), 256, 0, stream>>>(out, out_size);
        return;
    }

    char* ws = (char*)d_ws;
    f16*   xn_h  = (f16*)(ws);                         // [0,16) -> y_h later
    f16*   xbuf_h= (f16*)(ws + (16ull << 20));         // [16,32)
    f16*   zbuf_h= (f16*)(ws + (32ull << 20));         // [32,48)
    f16*   xc_h  = (f16*)(ws + (48ull << 20));         // [48,64)
    f16*   wih   = (f16*)(ws + (64ull << 20));         // [64,68)
    f16*   woh   = (f16*)(ws + (68ull << 20));         // [68,70)
    f16*   wxh   = (f16*)(ws + (70ull << 20));         // 160 KB
    f16*   wdh   = (f16*)(ws + (70ull << 20) + (512ull << 10));  // 128 KB
    float* dbl_f = (float*)(ws + (71ull << 20));       // 2.5 MB
    f16*   dth   = (f16*)(ws + (75ull << 20));         // [75,91)
    float* hF    = (float*)(ws + (91ull << 20));       // 8 MB
    float* Pb    = (float*)(ws + (99ull << 20));       // 8 MB
    float* h0    = (float*)(ws + (107ull << 20));      // 8 MB
    f16*   y_h   = xn_h;

    prep_kernel<<<dim3(WCVT_BLK + ZERO_BLK + NROWS), 256, 0, stream>>>(
        in_proj_w, x_proj_w, dt_proj_w, out_proj_w, wih, wxh, wdh, woh,
        dbl_f, hidden, norm_w, xn_h);
    // in_proj: M=8192 N=2048 K=1024 -> grid 32x8 = 256 blocks (1/CU), KT=16
    gemm1b<0><<<dim3(32, 8), 512, 0, stream>>>(xn_h, 1024, wih, 1024,
                                               xbuf_h, zbuf_h, 16);
    conv_silu_kernel<<<dim3(NROWS / 4, 4), 256, 0, stream>>>(xbuf_h, conv_w, conv_b, xc_h);
    gemm_f16<2, 0><<<dim3(64, 1, 4), 256, 0, stream>>>(xc_h, 1024, wxh, 1024,
                                                       dbl_f, nullptr, 80, 80, 256, nullptr);
    dtproj_kernel<<<dim3(64, 8), 256, 0, stream>>>(dbl_f, wdh, dth, dt_proj_b);
    scan1_kernel<<<dim3(4, NCHUNK, 4), 256, 0, stream>>>(dth, xc_h, dbl_f, A_log, hF, Pb);
    combine_kernel<<<dim3(128), 256, 0, stream>>>(hF, Pb, h0);
    scan2_kernel<<<dim3(4, NCHUNK, 4), 256, 0, stream>>>(dth, xc_h, dbl_f, A_log, h0,
                                                         zbuf_h, D_skip, y_h);
    gemm_f16<1, 0><<<dim3(64, 8), 256, 0, stream>>>(y_h, 1024, woh, 1024,
                                                    out, nullptr, 1024, 1024, 1024, nullptr);
}